// Round 4
// baseline (127.493 us; speedup 1.0000x reference)
//
#include <hip/hip_runtime.h>

// DatasetProjector: per-example Conv1d(200ch->512-of-4096, k=3, pad=1) + bias + GELU,
// computing only dataset_id[b]'s 512-channel slice (8x algebraic cut).
//
// R4: (1) corrected LDS granule swizzle s = p ^ ((row>>1)&3): every 16-lane quarter
// of a b128 read now spans all 8 granule phases (32 banks) -> conflict-free;
// (2) 512-thread blocks, 128m x 512t tile (8 waves, 2m x 4t), grid = 256 = 1 block/CU:
// MFMA per barrier doubles, W staging/re-reads halve. Register occupancy (216/wave ->
// 2 waves/SIMD) unchanged. LDS 57.5 KB.
// Note: ~78us/iter of total dur is harness d_ws/d_out re-poison fills (uncontrollable).

typedef unsigned short u16;
typedef __attribute__((ext_vector_type(8))) short bf16x8;
typedef __attribute__((ext_vector_type(4))) float f32x4;

#define CIN 200
#define CINP 224        // padded channels = 7 chunks of 32
#define T 1024
#define BATCH 32
#define MD 512
#define XT_ROWS 1026    // row t1 = t+1; rows 0 and 1025 are zeros
#define NCHUNK 7
#define XP_PITCH 202    // prep LDS pitch in u16 -> 101 dwords (odd => conflict-free)
#define TT 512          // t-tile
#define XROWS (TT + 2)  // 514 staged x rows (t0-1 .. t0+512)
#define XGRAN (XROWS * 4)   // 2056 16B granules = 32.9 KB
#define WGRAN 1536          // 3 taps x 128 m x 4 granules = 24.6 KB

__device__ __forceinline__ u16 f2bf(float f) {
    unsigned u = __float_as_uint(f);
    u += 0x7FFFu + ((u >> 16) & 1u);   // RNE
    return (u16)(u >> 16);
}

// async global(16B) -> LDS, dest = wave-uniform base + lane*16
__device__ __forceinline__ void g2l16(void* lds, const void* g) {
    __builtin_amdgcn_global_load_lds(
        (const __attribute__((address_space(1))) unsigned int*)(uintptr_t)g,
        (__attribute__((address_space(3))) unsigned int*)(unsigned)(uintptr_t)lds,
        16, 0, 0);
}

// ---- fused prep: blocks [0,512) transpose x -> xt[b][t+1][224] bf16;
//      blocks [512, 512+3584) transform W[o][i][k] -> wt[o][k][224] bf16 ----
__global__ __launch_bounds__(256) void prep(const float* __restrict__ x,
                                            const float* __restrict__ W,
                                            u16* __restrict__ xt,
                                            u16* __restrict__ wt) {
    __shared__ u16 tile[64 * XP_PITCH];
    const int tid = threadIdx.x;
    if (blockIdx.x < 512) {
        const int b  = blockIdx.x >> 4;
        const int bx = blockIdx.x & 15;
        const int t0 = bx * 64;
        const int tl = tid & 63;       // t within tile (lane -> coalesced x reads)
        const int w  = tid >> 6;
        const float* xb = x + (size_t)b * CIN * T + t0 + tl;
        for (int i = w; i < CIN; i += 4)                 // LDS row pitch 101 dwords (odd) -> conflict-free
            tile[tl * XP_PITCH + i] = f2bf(xb[(size_t)i * T]);
        __syncthreads();
        u16* xrow = xt + ((size_t)b * XT_ROWS + 1 + t0) * CINP;
        for (int it = 0; it < 16; ++it) {
            int r = it * 4 + w;
            if (tl < 56) {                               // 56 lanes x ushort4 = 224 ch
                ushort4 v = {0, 0, 0, 0};
                if (tl < 50) {                           // 50*4 = 200 valid channels
                    const u16* p = tile + r * XP_PITCH + tl * 4;
                    v.x = p[0]; v.y = p[1]; v.z = p[2]; v.w = p[3];
                }
                *(ushort4*)(xrow + (size_t)r * CINP + tl * 4) = v;
            }
        }
        if (bx == 0 && tid < 112)
            ((unsigned*)(xt + (size_t)b * XT_ROWS * CINP))[tid] = 0;          // t = -1 row
        if (bx == 15 && tid < 112)
            ((unsigned*)(xt + ((size_t)b * XT_ROWS + 1025) * CINP))[tid] = 0; // t = 1024 row
    } else {
        int idx = (blockIdx.x - 512) * 256 + tid;        // over 4096*224
        int o = idx / CINP;
        int i = idx - o * CINP;                          // i < 224 < 256 always valid in W
        const float* wp = W + (size_t)o * 768 + i * 3;   // 3 contiguous floats
        u16* wo = wt + (size_t)o * 3 * CINP + i;
        float w0 = wp[0], w1 = wp[1], w2 = wp[2];
        wo[0]        = f2bf(w0);
        wo[CINP]     = f2bf(w1);
        wo[2 * CINP] = f2bf(w2);
    }
}

// ---- main: per-example MFMA conv-GEMM, 128m x 512t per block, 256 blocks ----
// LDS granule swizzle: logical (row, seg s) stored at granule row*4 + (s ^ ((row>>1)&3));
// swizzle lives in the *global* gather address so global_load_lds (contiguous lane-order
// dest) and ds_read_b128 frag reads are both conflict-free (every 16-lane quarter spans
// all 8 granule phases = 32 banks).
__global__ __launch_bounds__(512, 2) void conv_mfma(const u16* __restrict__ xt,
                                                    const u16* __restrict__ wt,
                                                    const int* __restrict__ dsid,
                                                    const float* __restrict__ bias,
                                                    float* __restrict__ out) {
    __shared__ __align__(16) u16 xs[XGRAN * 8];    // 32.9 KB
    __shared__ __align__(16) u16 wsm[WGRAN * 8];   // 24.6 KB

    const int tid = threadIdx.x;
    const int wave = tid >> 6, lane = tid & 63;
    const int l = lane & 15, quad = lane >> 4;
    const int wm  = (wave & 1) * 64;       // wave m offset (2 m-waves)
    const int wti = (wave >> 1) * 128;     // wave t offset (4 t-waves)

    // XCD-aware swizzle: ids {k, k+8, k+16, k+24} = the 4 m-blocks of one (b,t)
    // -> same (id % 8) -> same XCD -> xt slice fetched once per XCD.
    const int id = blockIdx.x;
    const int tb = (id >> 5) * 8 + (id & 7);   // 0..63 = (b, tloc)
    const int m0 = ((id >> 3) & 3) * 128;
    const int t0 = (tb & 1) * TT;
    const int b  = tb >> 1;
    const int d  = dsid[b];
    const int obase = d * MD + m0;

    f32x4 acc[4][8];
#pragma unroll
    for (int mi = 0; mi < 4; ++mi)
#pragma unroll
        for (int ti = 0; ti < 8; ++ti) acc[mi][ti] = (f32x4){0.f, 0.f, 0.f, 0.f};

    const u16* xbase = xt + ((size_t)b * XT_ROWS + t0) * CINP;  // row r -> t = t0+r-1
    const u16* wbase = wt + (size_t)obase * 3 * CINP;

    // hoisted staging addresses (chunk-invariant); chunk advance = +32 u16 = 64 B
    const u16* xsrc[5]; u16* xdst[5];
#pragma unroll
    for (int k = 0; k < 5; ++k) {
        int g = tid + k * 512;
        int r = g >> 2, p = g & 3, s = p ^ ((r >> 1) & 3);
        if (g < XGRAN) { xsrc[k] = xbase + (size_t)r * CINP + s * 8; xdst[k] = xs + (size_t)(g & ~63) * 8; }
        else           { xsrc[k] = xbase;                            xdst[k] = xs; }
    }
    const u16* wsrc[3]; u16* wdst[3];
#pragma unroll
    for (int k = 0; k < 3; ++k) {
        int g = tid + k * 512;
        int p = g & 3, m = (g >> 2) & 127, kk = g >> 9;
        int s = p ^ ((m >> 1) & 3);
        wsrc[k] = wbase + ((size_t)m * 3 + kk) * CINP + s * 8;
        wdst[k] = wsm + (size_t)(g & ~63) * 8;
    }

    for (int c = 0; c < NCHUNK; ++c) {
        const int ic = c * 32;
#pragma unroll
        for (int k = 0; k < 5; ++k)
            if (tid + k * 512 < XGRAN) g2l16(xdst[k], xsrc[k] + ic);
#pragma unroll
        for (int k = 0; k < 3; ++k)
            g2l16(wdst[k], wsrc[k] + ic);
        __syncthreads();   // compiler emits vmcnt(0) drain before s_barrier

#pragma unroll
        for (int tap = 0; tap < 3; ++tap) {
            bf16x8 a[4];
#pragma unroll
            for (int mi = 0; mi < 4; ++mi) {
                int mr = tap * 128 + wm + mi * 16 + l;
                a[mi] = *(const bf16x8*)(wsm + ((size_t)mr * 4 + (quad ^ ((mr >> 1) & 3))) * 8);
            }
#pragma unroll
            for (int ti = 0; ti < 8; ++ti) {
                int row = wti + ti * 16 + l + tap;
                bf16x8 bv = *(const bf16x8*)(xs + ((size_t)row * 4 + (quad ^ ((row >> 1) & 3))) * 8);
#pragma unroll
                for (int mi = 0; mi < 4; ++mi)
                    acc[mi][ti] = __builtin_amdgcn_mfma_f32_16x16x32_bf16(a[mi], bv, acc[mi][ti], 0, 0, 0);
            }
        }
        __syncthreads();
    }

    // epilogue: +bias, sigmoid-form tanh-GELU (exp2-folded, branchless), f32 store
#pragma unroll
    for (int mi = 0; mi < 4; ++mi) {
        float bv[4];
#pragma unroll
        for (int r = 0; r < 4; ++r)
            bv[r] = bias[obase + wm + mi * 16 + quad * 4 + r];
#pragma unroll
        for (int ti = 0; ti < 8; ++ti) {
            int t = t0 + wti + ti * 16 + l;
#pragma unroll
            for (int r = 0; r < 4; ++r) {
                int m = wm + mi * 16 + quad * 4 + r;
                float v = acc[mi][ti][r] + bv[r];
                float p2 = v * v;
                // exp(-z), z = v*(1.59577 + 0.0713548 v^2), folded to exp2
                float z2 = v * fmaf(p2, -0.10295089f, -2.30243665f);
                float e = __builtin_amdgcn_exp2f(z2);
                float g = v * __builtin_amdgcn_rcpf(1.0f + e);   // v * sigmoid(z)
                out[((size_t)(b * MD + m0 + m)) * T + t] = g;
            }
        }
    }
}

extern "C" void kernel_launch(void* const* d_in, const int* in_sizes, int n_in,
                              void* d_out, int out_size, void* d_ws, size_t ws_size,
                              hipStream_t stream) {
    const float* x    = (const float*)d_in[0];
    const int*   dsid = (const int*)d_in[1];
    const float* W    = (const float*)d_in[2];
    const float* bias = (const float*)d_in[3];
    float* out = (float*)d_out;

    u16* xt = (u16*)d_ws;                                // 32*1026*224*2 = 14.7 MB
    u16* wt = xt + (size_t)BATCH * XT_ROWS * CINP;       // 4096*672*2   =  5.5 MB

    prep<<<512 + 3584, 256, 0, stream>>>(x, W, xt, wt);
    conv_mfma<<<256, 512, 0, stream>>>(xt, wt, dsid, bias, out);
}

// Round 5
// 122.184 us; speedup vs baseline: 1.0434x; 1.0434x over previous
//
#include <hip/hip_runtime.h>

// DatasetProjector: per-example Conv1d(200ch->512-of-4096, k=3, pad=1) + bias + GELU,
// computing only dataset_id[b]'s 512-channel slice (8x algebraic cut).
//
// R5 = R3 shape + R4 swizzle: 128m x 256t tile, 256-thread blocks, 512 blocks
// (2 blocks/CU -> cross-block overlap hides the vmcnt(0) barrier drain; R4 proved
// 1 block/CU exposes it, +18us) with the corrected conflict-free LDS granule
// swizzle s = p ^ ((row>>1)&3) (R4 measured SQ_LDS_BANK_CONFLICT == 0).
// Note: ~78us/iter of total dur is harness d_ws/d_out re-poison fills (uncontrollable).

typedef unsigned short u16;
typedef __attribute__((ext_vector_type(8))) short bf16x8;
typedef __attribute__((ext_vector_type(4))) float f32x4;

#define CIN 200
#define CINP 224        // padded channels = 7 chunks of 32
#define T 1024
#define BATCH 32
#define MD 512
#define XT_ROWS 1026    // row t1 = t+1; rows 0 and 1025 are zeros
#define NCHUNK 7
#define XP_PITCH 202    // prep LDS pitch in u16 -> 101 dwords (odd => conflict-free)
#define TT 256          // t-tile
#define XROWS (TT + 2)  // 258 staged x rows (t0-1 .. t0+256)
#define XGRAN (XROWS * 4)   // 1032 16B granules = 16.5 KB
#define WGRAN 1536          // 3 taps x 128 m x 4 granules = 24.6 KB

__device__ __forceinline__ u16 f2bf(float f) {
    unsigned u = __float_as_uint(f);
    u += 0x7FFFu + ((u >> 16) & 1u);   // RNE
    return (u16)(u >> 16);
}

// async global(16B) -> LDS, dest = wave-uniform base + lane*16
__device__ __forceinline__ void g2l16(void* lds, const void* g) {
    __builtin_amdgcn_global_load_lds(
        (const __attribute__((address_space(1))) unsigned int*)(uintptr_t)g,
        (__attribute__((address_space(3))) unsigned int*)(unsigned)(uintptr_t)lds,
        16, 0, 0);
}

// ---- fused prep: blocks [0,512) transpose x -> xt[b][t+1][224] bf16;
//      blocks [512, 512+3584) transform W[o][i][k] -> wt[o][k][224] bf16 ----
__global__ __launch_bounds__(256) void prep(const float* __restrict__ x,
                                            const float* __restrict__ W,
                                            u16* __restrict__ xt,
                                            u16* __restrict__ wt) {
    __shared__ u16 tile[64 * XP_PITCH];
    const int tid = threadIdx.x;
    if (blockIdx.x < 512) {
        const int b  = blockIdx.x >> 4;
        const int bx = blockIdx.x & 15;
        const int t0 = bx * 64;
        const int tl = tid & 63;       // t within tile (lane -> coalesced x reads)
        const int w  = tid >> 6;
        const float* xb = x + (size_t)b * CIN * T + t0 + tl;
        for (int i = w; i < CIN; i += 4)                 // LDS row pitch 101 dwords (odd) -> conflict-free
            tile[tl * XP_PITCH + i] = f2bf(xb[(size_t)i * T]);
        __syncthreads();
        u16* xrow = xt + ((size_t)b * XT_ROWS + 1 + t0) * CINP;
        for (int it = 0; it < 16; ++it) {
            int r = it * 4 + w;
            if (tl < 56) {                               // 56 lanes x ushort4 = 224 ch
                ushort4 v = {0, 0, 0, 0};
                if (tl < 50) {                           // 50*4 = 200 valid channels
                    const u16* p = tile + r * XP_PITCH + tl * 4;
                    v.x = p[0]; v.y = p[1]; v.z = p[2]; v.w = p[3];
                }
                *(ushort4*)(xrow + (size_t)r * CINP + tl * 4) = v;
            }
        }
        if (bx == 0 && tid < 112)
            ((unsigned*)(xt + (size_t)b * XT_ROWS * CINP))[tid] = 0;          // t = -1 row
        if (bx == 15 && tid < 112)
            ((unsigned*)(xt + ((size_t)b * XT_ROWS + 1025) * CINP))[tid] = 0; // t = 1024 row
    } else {
        int idx = (blockIdx.x - 512) * 256 + tid;        // over 4096*224
        int o = idx / CINP;
        int i = idx - o * CINP;                          // i < 224 < 256 always valid in W
        const float* wp = W + (size_t)o * 768 + i * 3;   // 3 contiguous floats
        u16* wo = wt + (size_t)o * 3 * CINP + i;
        float w0 = wp[0], w1 = wp[1], w2 = wp[2];
        wo[0]        = f2bf(w0);
        wo[CINP]     = f2bf(w1);
        wo[2 * CINP] = f2bf(w2);
    }
}

// ---- main: per-example MFMA conv-GEMM, 128m x 256t per block, 512 blocks ----
// LDS granule swizzle: logical (row, seg s) stored at granule row*4 + (s ^ ((row>>1)&3));
// swizzle lives in the *global* gather address so global_load_lds (contiguous lane-order
// dest) and ds_read_b128 frag reads are both conflict-free (every 16-lane quarter of a
// b128 read spans all 8 granule phases = 32 banks; R4 measured 0 conflicts).
__global__ __launch_bounds__(256, 2) void conv_mfma(const u16* __restrict__ xt,
                                                    const u16* __restrict__ wt,
                                                    const int* __restrict__ dsid,
                                                    const float* __restrict__ bias,
                                                    float* __restrict__ out) {
    __shared__ __align__(16) u16 xs[XGRAN * 8];    // 16.5 KB
    __shared__ __align__(16) u16 wsm[WGRAN * 8];   // 24.6 KB

    const int tid = threadIdx.x;
    const int wave = tid >> 6, lane = tid & 63;
    const int l = lane & 15, quad = lane >> 4;
    const int wm  = (wave & 1) * 64;       // wave m offset (2 m-waves)
    const int wti = (wave >> 1) * 128;     // wave t offset (2 t-waves)

    // XCD-aware swizzle: ids {k, k+8, k+16, k+24} = the 4 m-blocks of one (b,t)
    // -> same (id % 8) -> same XCD -> xt slice fetched once per XCD.
    const int id = blockIdx.x;
    const int tb = (id >> 5) * 8 + (id & 7);   // 0..127 = (b, tloc)
    const int m0 = ((id >> 3) & 3) * 128;
    const int t0 = (tb & 3) * TT;
    const int b  = tb >> 2;
    const int d  = dsid[b];
    const int obase = d * MD + m0;

    f32x4 acc[4][8];
#pragma unroll
    for (int mi = 0; mi < 4; ++mi)
#pragma unroll
        for (int ti = 0; ti < 8; ++ti) acc[mi][ti] = (f32x4){0.f, 0.f, 0.f, 0.f};

    const u16* xbase = xt + ((size_t)b * XT_ROWS + t0) * CINP;  // row r -> t = t0+r-1
    const u16* wbase = wt + (size_t)obase * 3 * CINP;

    // hoisted staging addresses (chunk-invariant); chunk advance = +32 u16 = 64 B
    const u16* xsrc[5]; u16* xdst[5];
#pragma unroll
    for (int k = 0; k < 5; ++k) {
        int g = tid + k * 256;
        int r = g >> 2, p = g & 3, s = p ^ ((r >> 1) & 3);
        if (g < XGRAN) { xsrc[k] = xbase + (size_t)r * CINP + s * 8; xdst[k] = xs + (size_t)(g & ~63) * 8; }
        else           { xsrc[k] = xbase;                            xdst[k] = xs; }
    }
    const u16* wsrc[6]; u16* wdst[6];
#pragma unroll
    for (int k = 0; k < 6; ++k) {
        int g = tid + k * 256;
        int p = g & 3, m = (g >> 2) & 127, kk = g >> 9;
        int s = p ^ ((m >> 1) & 3);
        wsrc[k] = wbase + ((size_t)m * 3 + kk) * CINP + s * 8;
        wdst[k] = wsm + (size_t)(g & ~63) * 8;
    }

    for (int c = 0; c < NCHUNK; ++c) {
        const int ic = c * 32;
#pragma unroll
        for (int k = 0; k < 5; ++k)
            if (tid + k * 256 < XGRAN) g2l16(xdst[k], xsrc[k] + ic);
#pragma unroll
        for (int k = 0; k < 6; ++k)
            g2l16(wdst[k], wsrc[k] + ic);
        __syncthreads();   // vmcnt(0) drain here; hidden by the co-resident block

#pragma unroll
        for (int tap = 0; tap < 3; ++tap) {
            bf16x8 a[4];
#pragma unroll
            for (int mi = 0; mi < 4; ++mi) {
                int mr = tap * 128 + wm + mi * 16 + l;
                a[mi] = *(const bf16x8*)(wsm + ((size_t)mr * 4 + (quad ^ ((mr >> 1) & 3))) * 8);
            }
#pragma unroll
            for (int ti = 0; ti < 8; ++ti) {
                int row = wti + ti * 16 + l + tap;
                bf16x8 bv = *(const bf16x8*)(xs + ((size_t)row * 4 + (quad ^ ((row >> 1) & 3))) * 8);
#pragma unroll
                for (int mi = 0; mi < 4; ++mi)
                    acc[mi][ti] = __builtin_amdgcn_mfma_f32_16x16x32_bf16(a[mi], bv, acc[mi][ti], 0, 0, 0);
            }
        }
        __syncthreads();
    }

    // epilogue: +bias, sigmoid-form tanh-GELU (exp2-folded, branchless), f32 store
#pragma unroll
    for (int mi = 0; mi < 4; ++mi) {
        float bv[4];
#pragma unroll
        for (int r = 0; r < 4; ++r)
            bv[r] = bias[obase + wm + mi * 16 + quad * 4 + r];
#pragma unroll
        for (int ti = 0; ti < 8; ++ti) {
            int t = t0 + wti + ti * 16 + l;
#pragma unroll
            for (int r = 0; r < 4; ++r) {
                int m = wm + mi * 16 + quad * 4 + r;
                float v = acc[mi][ti][r] + bv[r];
                float p2 = v * v;
                // exp(-z), z = v*(1.59577 + 0.0713548 v^2), folded to exp2
                float z2 = v * fmaf(p2, -0.10295089f, -2.30243665f);
                float e = __builtin_amdgcn_exp2f(z2);
                float g = v * __builtin_amdgcn_rcpf(1.0f + e);   // v * sigmoid(z)
                out[((size_t)(b * MD + m0 + m)) * T + t] = g;
            }
        }
    }
}

extern "C" void kernel_launch(void* const* d_in, const int* in_sizes, int n_in,
                              void* d_out, int out_size, void* d_ws, size_t ws_size,
                              hipStream_t stream) {
    const float* x    = (const float*)d_in[0];
    const int*   dsid = (const int*)d_in[1];
    const float* W    = (const float*)d_in[2];
    const float* bias = (const float*)d_in[3];
    float* out = (float*)d_out;

    u16* xt = (u16*)d_ws;                                // 32*1026*224*2 = 14.7 MB
    u16* wt = xt + (size_t)BATCH * XT_ROWS * CINP;       // 4096*672*2   =  5.5 MB

    prep<<<512 + 3584, 256, 0, stream>>>(x, W, xt, wt);
    conv_mfma<<<512, 256, 0, stream>>>(xt, wt, dsid, bias, out);
}